// Round 1
// baseline (240.472 us; speedup 1.0000x reference)
//
#include <hip/hip_runtime.h>
#include <hip/hip_bf16.h>

// Problem constants (shapes fixed by setup_inputs): nw_out [N=4, C=19, H=512, W=1024] fp32.
#define N_IMG 4
#define C_CLS 19
#define HW    (512 * 1024)          // per-image, per-channel plane
#define NPIX  (N_IMG * HW)          // 2,097,152 pixels
#define VPIX  (NPIX / 4)            // 524,288 float4 pixel-groups
#define IW    0.2f

typedef float f4 __attribute__((ext_vector_type(4)));

// ---------------------------------------------------------------------------
// Kernel 1: zero the 2*C_CLS float workspace (harness poisons d_ws each call).
// ---------------------------------------------------------------------------
__global__ void zero_ws(float* ws) {
    int t = threadIdx.x;
    if (t < 2 * C_CLS) ws[t] = 0.0f;
}

// ---------------------------------------------------------------------------
// Kernel 2: single full pass over the input.
// Per pixel: argmax class (pred), s = sum(prob^2) via stable softmax.
// Accumulate per-class {sum of s, count} into LDS, then 19 global atomics/blk.
// ---------------------------------------------------------------------------
__global__ __launch_bounds__(256) void main_pass(const float* __restrict__ x,
                                                 float* __restrict__ gsum,
                                                 float* __restrict__ gcnt) {
    __shared__ float s_sum[C_CLS];
    __shared__ float s_cnt[C_CLS];
    const int t = threadIdx.x;
    if (t < C_CLS) { s_sum[t] = 0.0f; s_cnt[t] = 0.0f; }
    __syncthreads();

    // vec4 pixel-group index; grid exactly covers VPIX (2048 blocks * 256).
    const int v   = blockIdx.x * 256 + t;
    const int n   = v >> 17;                 // v / (HW/4), HW/4 = 131072 = 2^17
    const int hw4 = v & (131072 - 1);
    const float* base = x + (size_t)n * C_CLS * HW + (size_t)hw4 * 4;

    // Load all 19 channels x 4 pixels into registers (coalesced dwordx4).
    f4 val[C_CLS];
#pragma unroll
    for (int c = 0; c < C_CLS; ++c)
        val[c] = *(const f4*)(base + (size_t)c * HW);

#pragma unroll
    for (int j = 0; j < 4; ++j) {
        // argmax (first-max semantics, matches jnp.argmax) + max for stability
        float m = val[0][j];
        int   am = 0;
#pragma unroll
        for (int c = 1; c < C_CLS; ++c) {
            float xv = val[c][j];
            if (xv > m) { m = xv; am = c; }
        }
        // l = sum exp(x-m), q = sum exp(x-m)^2 ; s = q / l^2 = sum(prob^2)
        float l = 0.0f, q = 0.0f;
#pragma unroll
        for (int c = 0; c < C_CLS; ++c) {
            float e = __expf(val[c][j] - m);
            l += e;
            q += e * e;
        }
        float s = q / (l * l);
        atomicAdd(&s_sum[am], s);
        atomicAdd(&s_cnt[am], 1.0f);   // exact: integer-valued fp32 < 2^24
    }

    __syncthreads();
    if (t < C_CLS) {
        atomicAdd(&gsum[t], s_sum[t]);
        atomicAdd(&gcnt[t], s_cnt[t]);
    }
}

// ---------------------------------------------------------------------------
// Kernel 3: den_c = max(hist^0.2 * Np^0.8, 1); out = -sum_c(gsum[c]/den_c)/(N*C)
// ---------------------------------------------------------------------------
__global__ void finalize(const float* __restrict__ gsum,
                         const float* __restrict__ gcnt,
                         float* __restrict__ out) {
    const int t = threadIdx.x;   // one wave of 64
    float vsum = 0.0f;
    if (t < C_CLS) {
        const float scale = powf((float)NPIX, 1.0f - IW);   // Np^0.8
        float den = fmaxf(powf(gcnt[t], IW) * scale, 1.0f);
        vsum = gsum[t] / den;
    }
#pragma unroll
    for (int off = 32; off > 0; off >>= 1)
        vsum += __shfl_down(vsum, off);
    if (t == 0)
        out[0] = -vsum / (float)(N_IMG * C_CLS);
}

extern "C" void kernel_launch(void* const* d_in, const int* in_sizes, int n_in,
                              void* d_out, int out_size, void* d_ws, size_t ws_size,
                              hipStream_t stream) {
    const float* x = (const float*)d_in[0];
    float* out  = (float*)d_out;
    float* gsum = (float*)d_ws;          // [C_CLS]
    float* gcnt = gsum + C_CLS;          // [C_CLS]

    zero_ws<<<1, 64, 0, stream>>>(gsum);
    main_pass<<<VPIX / 256, 256, 0, stream>>>(x, gsum, gcnt);
    finalize<<<1, 64, 0, stream>>>(gsum, gcnt, out);
}